// Round 9
// baseline (263.456 us; speedup 1.0000x reference)
//
#include <hip/hip_runtime.h>
#include <hip/hip_cooperative_groups.h>

namespace cg = cooperative_groups;

#define B_ 64
#define NB_ 8
#define Q_ 32
#define T_ 256
#define D_ 256
#define NBINS 11

typedef __attribute__((ext_vector_type(8))) short bf16x8;
typedef __attribute__((ext_vector_type(4))) float f32x4;
typedef unsigned short ushort_t;
typedef unsigned int uint_t;

// ws byte offsets: fragment-ordered bf16 hi/lo split of can + psum.
#define CANH_OFF 0u
#define CANL_OFF 8388608u
#define PSUM_OFF 16777216u

__device__ inline ushort_t bf16_rnd(float f) {
  uint_t u = __float_as_uint(f);
  return (ushort_t)((u + 0x8000u) >> 16);
}
__device__ inline uint_t pack2(ushort_t a, ushort_t b) {
  return (uint_t)a | ((uint_t)b << 16);
}

// ===========================================================================
// Fused cooperative kernel: 512 blocks x 256 threads, guaranteed co-resident
// (2 blocks/CU: LDS 2x33.8KB=67.6KB<160KB, ~130 VGPR < 256 for 2 waves/SIMD).
//   Phase A: can row-norm + hi/lo bf16 split -> fragment-ordered ws
//            (b = blk&63 so writer XCD == reader XCD == b%8)
//   grid.sync()
//   Phase B: pool — R8-validated barrier-free deferred-bins 3-MFMA pipeline,
//            in-register A split, psum written once per block
//   grid.sync()
//   Phase C: blocks 0..63 run the final epilogue (log-pool + attention).
// Replaces 3 dispatches with 1: saves ~2 graph-replay dispatch boundaries.
// ===========================================================================
__global__ __launch_bounds__(256) void fused_kernel(
    const float* __restrict__ can, const float* __restrict__ hq,
    const float* __restrict__ word_atten, const float* __restrict__ mask_hq,
    const float* __restrict__ mask_can, const float* __restrict__ rep,
    const float* __restrict__ rep_cur, const float* __restrict__ mask_session,
    const float* __restrict__ W_dense, const float* __restrict__ b_dense,
    const float* __restrict__ W_att, const float* __restrict__ b_att,
    uint4* __restrict__ canH, uint4* __restrict__ canL,
    float* __restrict__ psum, float* __restrict__ out) {
  __shared__ __align__(16) char smem[33792];  // phase-overlaid scratch
  ushort_t* sm_hi = (ushort_t*)smem;            // phase A: 16896 B
  ushort_t* sm_lo = (ushort_t*)(smem + 16896);  // phase A: 16896 B

  const float mus[NBINS] = {1.0f, 0.9f, 0.7f, 0.5f, 0.3f, 0.1f,
                            -0.1f, -0.3f, -0.5f, -0.7f, -0.9f};
  const float nis2[NBINS] = {-5.0e5f, -50.f, -50.f, -50.f, -50.f, -50.f,
                             -50.f, -50.f, -50.f, -50.f, -50.f};

  int blk = blockIdx.x;
  int tid = threadIdx.x;
  int wv = tid >> 6, lane = tid & 63;
  int lq = lane & 15, lk = lane >> 4;

  // ---------------- Phase A: split can (R8-validated body) ----------------
  {
    int b = blk & 63, ch = blk >> 6;  // XCD(blk)=blk%8=b%8 = phase-B reader
    const float* src = can + ((size_t)b * T_ + ch * 32) * D_;
    int tilebase = b * 16 + ch * 2;
#pragma unroll
    for (int it = 0; it < 4; it++) {
      int flat = it * 2048 + tid * 8;
      int row = flat >> 8, col = flat & 255;
      const float* p = src + row * D_ + col;
      float4 x = reinterpret_cast<const float4*>(p)[0];
      float4 y = reinterpret_cast<const float4*>(p)[1];
      float s = x.x * x.x + x.y * x.y + x.z * x.z + x.w * x.w +
                y.x * y.x + y.y * y.y + y.z * y.z + y.w * y.w;
      s += __shfl_xor(s, 1);
      s += __shfl_xor(s, 2);
      s += __shfl_xor(s, 4);
      s += __shfl_xor(s, 8);
      s += __shfl_xor(s, 16);
      float inv = 1.0f / fmaxf(sqrtf(s), 1e-10f);
      float v[8] = {x.x, x.y, x.z, x.w, y.x, y.y, y.z, y.w};
      ushort_t h[8], l[8];
#pragma unroll
      for (int j = 0; j < 8; j++) {
        float sv = v[j] * inv;
        h[j] = bf16_rnd(sv);
        float hf = __uint_as_float(((uint_t)h[j]) << 16);
        l[j] = bf16_rnd(sv - hf);
      }
      uint4 ph = {pack2(h[0], h[1]), pack2(h[2], h[3]), pack2(h[4], h[5]),
                  pack2(h[6], h[7])};
      uint4 pl = {pack2(l[0], l[1]), pack2(l[2], l[3]), pack2(l[4], l[5]),
                  pack2(l[6], l[7])};
      *reinterpret_cast<uint4*>(&sm_hi[row * 264 + col]) = ph;
      *reinterpret_cast<uint4*>(&sm_lo[row * 264 + col]) = pl;
    }
    __syncthreads();
    int tl = wv >> 1, part = wv & 1;
    const ushort_t* smp = part ? sm_lo : sm_hi;
    uint4* dst = part ? canL : canH;
#pragma unroll
    for (int kk = 0; kk < 8; kk++) {
      const ushort_t* a = &smp[(tl * 16 + lq) * 264 + kk * 32 + lk * 8];
      dst[((size_t)(tilebase + tl) * 8 + kk) * 64 + lane] =
          *reinterpret_cast<const uint4*>(a);
    }
  }

  cg::this_grid().sync();

  // ---------------- Phase B: pool (R8-validated body) ----------------
  {
    float* partial = (float*)smem;  // 2816 B overlay (phase-A data dead)
    int b = blk & 63;
    int nb = blk >> 6;
    int outb = b * NB_ + nb;
    int mtile = wv & 1, tq = wv >> 1;

    // A fragments: register norm + hi/lo split
    const float* arow =
        hq + (size_t)outb * (Q_ * D_) + (size_t)(mtile * 16 + lq) * D_;
    float sumsq = 0.f;
#pragma unroll
    for (int kk = 0; kk < 8; kk++) {
      const float* p = arow + kk * 32 + lk * 8;
      float4 x = reinterpret_cast<const float4*>(p)[0];
      float4 y = reinterpret_cast<const float4*>(p)[1];
      sumsq += x.x * x.x + x.y * x.y + x.z * x.z + x.w * x.w +
               y.x * y.x + y.y * y.y + y.z * y.z + y.w * y.w;
    }
    sumsq += __shfl_xor(sumsq, 16);
    sumsq += __shfl_xor(sumsq, 32);
    float ainv = 1.0f / fmaxf(sqrtf(sumsq), 1e-10f);

    bf16x8 ah[8], al[8];
#pragma unroll
    for (int kk = 0; kk < 8; kk++) {
      const float* p = arow + kk * 32 + lk * 8;  // L1-hot reload
      float4 x = reinterpret_cast<const float4*>(p)[0];
      float4 y = reinterpret_cast<const float4*>(p)[1];
      float v[8] = {x.x, x.y, x.z, x.w, y.x, y.y, y.z, y.w};
      union { bf16x8 v8; ushort_t u[8]; } H, L;
#pragma unroll
      for (int j = 0; j < 8; j++) {
        float s = v[j] * ainv;
        ushort_t h = bf16_rnd(s);
        float hf = __uint_as_float(((uint_t)h) << 16);
        H.u[j] = h;
        L.u[j] = bf16_rnd(s - hf);
      }
      ah[kk] = H.v8;
      al[kk] = L.v8;
    }

    float binacc[4][NBINS];
#pragma unroll
    for (int r = 0; r < 4; r++)
#pragma unroll
      for (int j = 0; j < NBINS; j++) binacc[r][j] = 0.0f;

    f32x4 accPrev;
    float mkPrev = 0.0f;

    {  // tile 0
      int tt = tq * 8;
      size_t bbase = (size_t)(b * 16 + tt) * 8 * 64 + lane;
      f32x4 acc = {0.f, 0.f, 0.f, 0.f};
#pragma unroll
      for (int kk = 0; kk < 8; kk++) {
        bf16x8 bh = *reinterpret_cast<const bf16x8*>(&canH[bbase + kk * 64]);
        bf16x8 bl = *reinterpret_cast<const bf16x8*>(&canL[bbase + kk * 64]);
        acc = __builtin_amdgcn_mfma_f32_16x16x32_bf16(ah[kk], bh, acc, 0, 0, 0);
        acc = __builtin_amdgcn_mfma_f32_16x16x32_bf16(al[kk], bh, acc, 0, 0, 0);
        acc = __builtin_amdgcn_mfma_f32_16x16x32_bf16(ah[kk], bl, acc, 0, 0, 0);
      }
      accPrev = acc;
      mkPrev = mask_can[b * T_ + tt * 16 + lq];
    }

    for (int ti = 1; ti < 8; ti++) {  // load(ti) before bins(ti-1)
      int tt = tq * 8 + ti;
      size_t bbase = (size_t)(b * 16 + tt) * 8 * 64 + lane;
      bf16x8 bh[8], bl[8];
#pragma unroll
      for (int kk = 0; kk < 8; kk++) {
        bh[kk] = *reinterpret_cast<const bf16x8*>(&canH[bbase + kk * 64]);
        bl[kk] = *reinterpret_cast<const bf16x8*>(&canL[bbase + kk * 64]);
      }
#pragma unroll
      for (int r = 0; r < 4; r++) {
        float v0 = accPrev[r];
#pragma unroll
        for (int j = 0; j < NBINS; j++) {
          float d0 = v0 - mus[j];
          binacc[r][j] += mkPrev * __expf(d0 * d0 * nis2[j]);
        }
      }
      f32x4 acc = {0.f, 0.f, 0.f, 0.f};
#pragma unroll
      for (int kk = 0; kk < 8; kk++) {
        acc = __builtin_amdgcn_mfma_f32_16x16x32_bf16(ah[kk], bh[kk], acc, 0, 0, 0);
        acc = __builtin_amdgcn_mfma_f32_16x16x32_bf16(al[kk], bh[kk], acc, 0, 0, 0);
        acc = __builtin_amdgcn_mfma_f32_16x16x32_bf16(ah[kk], bl[kk], acc, 0, 0, 0);
      }
      accPrev = acc;
      mkPrev = mask_can[b * T_ + tt * 16 + lq];
    }
#pragma unroll
    for (int r = 0; r < 4; r++) {  // bins of last tile
      float v0 = accPrev[r];
#pragma unroll
      for (int j = 0; j < NBINS; j++) {
        float d0 = v0 - mus[j];
        binacc[r][j] += mkPrev * __expf(d0 * d0 * nis2[j]);
      }
    }

    // reduce over 16 t-cols (lq)
#pragma unroll
    for (int r = 0; r < 4; r++)
#pragma unroll
      for (int j = 0; j < NBINS; j++) {
        float v = binacc[r][j];
        v += __shfl_xor(v, 1);
        v += __shfl_xor(v, 2);
        v += __shfl_xor(v, 4);
        v += __shfl_xor(v, 8);
        binacc[r][j] = v;
      }
    __syncthreads();  // phase-A smem reads fully retired before overlay write
    if (lq == 0) {
#pragma unroll
      for (int r = 0; r < 4; r++)
#pragma unroll
        for (int j = 0; j < NBINS; j++)
          partial[(wv * 16 + lk * 4 + r) * NBINS + j] = binacc[r][j];
    }
    __syncthreads();

    // combine tq halves; single psum write. STRIDED over 352 (R3 lesson).
    float* dst = &psum[(size_t)outb * (Q_ * NBINS)];
    for (int idx = tid; idx < Q_ * NBINS; idx += 256) {
      int q = idx / NBINS;
      int j = idx - q * NBINS;
      int m = q >> 4, r16 = q & 15;
      dst[idx] = partial[(m * 16 + r16) * NBINS + j] +
                 partial[((2 + m) * 16 + r16) * NBINS + j];
    }
  }

  cg::this_grid().sync();

  // ---------------- Phase C: final epilogue, blocks 0..63 ----------------
  if (blk < B_) {
    float* lp = (float*)smem;                 // 2816 f
    float* pooled_sm = lp + NB_ * Q_ * NBINS; // 88 f
    float* qproj = pooled_sm + NB_ * NBINS;   // 256 f
    float* scores_sm = qproj + D_;            // 8 f   (total 12.7 KB)
    int b = blk;

    {
      int nb = tid >> 5, q = tid & 31;
      int outb = b * NB_ + nb;
      float wa = word_atten[outb * Q_ + q] * mask_hq[outb * Q_ + q];
      const float* ps = &psum[(size_t)outb * (Q_ * NBINS) + q * NBINS];
#pragma unroll
      for (int j = 0; j < NBINS; j++)
        lp[(nb * Q_ + q) * NBINS + j] =
            logf(fmaxf(ps[j], 1e-10f)) * 0.01f * wa;
    }

    const float* rc = rep_cur + b * D_;
    float acc = b_att[tid];
    for (int k = 0; k < D_; k++) acc += rc[k] * W_att[k * D_ + tid];
    qproj[tid] = acc;
    __syncthreads();

    if (tid < NB_ * NBINS) {
      int nb = tid / NBINS, j = tid - nb * NBINS;
      float s = 0.f;
#pragma unroll
      for (int q = 0; q < Q_; q++) s += lp[(nb * Q_ + q) * NBINS + j];
      pooled_sm[nb * NBINS + j] = s;
    }

    for (int nn = wv; nn < NB_; nn += 4) {
      const float* rp = rep + ((size_t)b * NB_ + nn) * D_;
      float4 r4 = reinterpret_cast<const float4*>(rp)[lane];
      float4 q4 = *reinterpret_cast<float4*>(&qproj[lane * 4]);
      float s = r4.x * q4.x + r4.y * q4.y + r4.z * q4.z + r4.w * q4.w;
#pragma unroll
      for (int off = 32; off > 0; off >>= 1) s += __shfl_down(s, off);
      if (lane == 0) scores_sm[nn] = s * 0.0625f;  // 1/sqrt(256)
    }
    __syncthreads();

    if (tid == 0) {
      float sc[NB_];
      float mx = -1e30f;
      for (int nn = 0; nn < NB_; nn++) {
        float s = (mask_session[b * NB_ + nn] > 0.f) ? scores_sm[nn] : -1e9f;
        sc[nn] = s;
        mx = fmaxf(mx, s);
      }
      float den = 0.f;
      for (int nn = 0; nn < NB_; nn++) {
        sc[nn] = __expf(sc[nn] - mx);
        den += sc[nn];
      }
      float res = 0.f;
      for (int nn = 0; nn < NB_; nn++) {
        float ms = mask_session[b * NB_ + nn];
        float pw = b_dense[0];
        for (int j = 0; j < NBINS; j++)
          pw += pooled_sm[nn * NBINS + j] * ms * W_dense[j];
        res += tanhf(pw) * (sc[nn] / den);
      }
      out[b] = res;
    }
  }
}

// ===========================================================================
// Fallback path (cooperative enqueue fails): R8's validated 3 kernels.
// ===========================================================================
__global__ __launch_bounds__(256) void split_kernel(
    const float* __restrict__ can, uint4* __restrict__ canH,
    uint4* __restrict__ canL) {
  __shared__ __align__(16) ushort_t sm_hi[32 * 264];
  __shared__ __align__(16) ushort_t sm_lo[32 * 264];
  int blk = blockIdx.x;
  int tid = threadIdx.x;
  int b = blk >> 3, ch = blk & 7;
  const float* src = can + ((size_t)b * T_ + ch * 32) * D_;
  int tilebase = b * 16 + ch * 2;
#pragma unroll
  for (int it = 0; it < 4; it++) {
    int flat = it * 2048 + tid * 8;
    int row = flat >> 8, col = flat & 255;
    const float* p = src + row * D_ + col;
    float4 x = reinterpret_cast<const float4*>(p)[0];
    float4 y = reinterpret_cast<const float4*>(p)[1];
    float s = x.x * x.x + x.y * x.y + x.z * x.z + x.w * x.w +
              y.x * y.x + y.y * y.y + y.z * y.z + y.w * y.w;
    s += __shfl_xor(s, 1);
    s += __shfl_xor(s, 2);
    s += __shfl_xor(s, 4);
    s += __shfl_xor(s, 8);
    s += __shfl_xor(s, 16);
    float inv = 1.0f / fmaxf(sqrtf(s), 1e-10f);
    float v[8] = {x.x, x.y, x.z, x.w, y.x, y.y, y.z, y.w};
    ushort_t h[8], l[8];
#pragma unroll
    for (int j = 0; j < 8; j++) {
      float sv = v[j] * inv;
      h[j] = bf16_rnd(sv);
      float hf = __uint_as_float(((uint_t)h[j]) << 16);
      l[j] = bf16_rnd(sv - hf);
    }
    uint4 ph = {pack2(h[0], h[1]), pack2(h[2], h[3]), pack2(h[4], h[5]),
                pack2(h[6], h[7])};
    uint4 pl = {pack2(l[0], l[1]), pack2(l[2], l[3]), pack2(l[4], l[5]),
                pack2(l[6], l[7])};
    *reinterpret_cast<uint4*>(&sm_hi[row * 264 + col]) = ph;
    *reinterpret_cast<uint4*>(&sm_lo[row * 264 + col]) = pl;
  }
  __syncthreads();
  int wv = tid >> 6, lane = tid & 63;
  int tl = wv >> 1, part = wv & 1;
  int lq = lane & 15, lk = lane >> 4;
  const ushort_t* smp = part ? sm_lo : sm_hi;
  uint4* dst = part ? canL : canH;
#pragma unroll
  for (int kk = 0; kk < 8; kk++) {
    const ushort_t* a = &smp[(tl * 16 + lq) * 264 + kk * 32 + lk * 8];
    dst[((size_t)(tilebase + tl) * 8 + kk) * 64 + lane] =
        *reinterpret_cast<const uint4*>(a);
  }
}

__global__ __launch_bounds__(256, 2) void pool_kernel(
    const float* __restrict__ hq, const uint4* __restrict__ canH,
    const uint4* __restrict__ canL, const float* __restrict__ mask_can,
    float* __restrict__ psum) {
  __shared__ float partial[4 * 16 * NBINS];
  const float mus[NBINS] = {1.0f, 0.9f, 0.7f, 0.5f, 0.3f, 0.1f,
                            -0.1f, -0.3f, -0.5f, -0.7f, -0.9f};
  const float nis2[NBINS] = {-5.0e5f, -50.f, -50.f, -50.f, -50.f, -50.f,
                             -50.f, -50.f, -50.f, -50.f, -50.f};
  int i = blockIdx.x;
  int b = i & 63;
  int nb = i >> 6;
  int outb = b * NB_ + nb;
  int tid = threadIdx.x;
  int wv = tid >> 6, lane = tid & 63;
  int lq = lane & 15, lk = lane >> 4;
  int mtile = wv & 1, tq = wv >> 1;

  const float* arow =
      hq + (size_t)outb * (Q_ * D_) + (size_t)(mtile * 16 + lq) * D_;
  float sumsq = 0.f;
#pragma unroll
  for (int kk = 0; kk < 8; kk++) {
    const float* p = arow + kk * 32 + lk * 8;
    float4 x = reinterpret_cast<const float4*>(p)[0];
    float4 y = reinterpret_cast<const float4*>(p)[1];
    sumsq += x.x * x.x + x.y * x.y + x.z * x.z + x.w * x.w +
             y.x * y.x + y.y * y.y + y.z * y.z + y.w * y.w;
  }
  sumsq += __shfl_xor(sumsq, 16);
  sumsq += __shfl_xor(sumsq, 32);
  float ainv = 1.0f / fmaxf(sqrtf(sumsq), 1e-10f);

  bf16x8 ah[8], al[8];
#pragma unroll
  for (int kk = 0; kk < 8; kk++) {
    const float* p = arow + kk * 32 + lk * 8;
    float4 x = reinterpret_cast<const float4*>(p)[0];
    float4 y = reinterpret_cast<const float4*>(p)[1];
    float v[8] = {x.x, x.y, x.z, x.w, y.x, y.y, y.z, y.w};
    union { bf16x8 v8; ushort_t u[8]; } H, L;
#pragma unroll
    for (int j = 0; j < 8; j++) {
      float s = v[j] * ainv;
      ushort_t h = bf16_rnd(s);
      float hf = __uint_as_float(((uint_t)h) << 16);
      H.u[j] = h;
      L.u[j] = bf16_rnd(s - hf);
    }
    ah[kk] = H.v8;
    al[kk] = L.v8;
  }

  float binacc[4][NBINS];
#pragma unroll
  for (int r = 0; r < 4; r++)
#pragma unroll
    for (int j = 0; j < NBINS; j++) binacc[r][j] = 0.0f;

  f32x4 accPrev;
  float mkPrev = 0.0f;
  {
    int tt = tq * 8;
    size_t bbase = (size_t)(b * 16 + tt) * 8 * 64 + lane;
    f32x4 acc = {0.f, 0.f, 0.f, 0.f};
#pragma unroll
    for (int kk = 0; kk < 8; kk++) {
      bf16x8 bh = *reinterpret_cast<const bf16x8*>(&canH[bbase + kk * 64]);
      bf16x8 bl = *reinterpret_cast<const bf16x8*>(&canL[bbase + kk * 64]);
      acc = __builtin_amdgcn_mfma_f32_16x16x32_bf16(ah[kk], bh, acc, 0, 0, 0);
      acc = __builtin_amdgcn_mfma_f32_16x16x32_bf16(al[kk], bh, acc, 0, 0, 0);
      acc = __builtin_amdgcn_mfma_f32_16x16x32_bf16(ah[kk], bl, acc, 0, 0, 0);
    }
    accPrev = acc;
    mkPrev = mask_can[b * T_ + tt * 16 + lq];
  }
  for (int ti = 1; ti < 8; ti++) {
    int tt = tq * 8 + ti;
    size_t bbase = (size_t)(b * 16 + tt) * 8 * 64 + lane;
    bf16x8 bh[8], bl[8];
#pragma unroll
    for (int kk = 0; kk < 8; kk++) {
      bh[kk] = *reinterpret_cast<const bf16x8*>(&canH[bbase + kk * 64]);
      bl[kk] = *reinterpret_cast<const bf16x8*>(&canL[bbase + kk * 64]);
    }
#pragma unroll
    for (int r = 0; r < 4; r++) {
      float v0 = accPrev[r];
#pragma unroll
      for (int j = 0; j < NBINS; j++) {
        float d0 = v0 - mus[j];
        binacc[r][j] += mkPrev * __expf(d0 * d0 * nis2[j]);
      }
    }
    f32x4 acc = {0.f, 0.f, 0.f, 0.f};
#pragma unroll
    for (int kk = 0; kk < 8; kk++) {
      acc = __builtin_amdgcn_mfma_f32_16x16x32_bf16(ah[kk], bh[kk], acc, 0, 0, 0);
      acc = __builtin_amdgcn_mfma_f32_16x16x32_bf16(al[kk], bh[kk], acc, 0, 0, 0);
      acc = __builtin_amdgcn_mfma_f32_16x16x32_bf16(ah[kk], bl[kk], acc, 0, 0, 0);
    }
    accPrev = acc;
    mkPrev = mask_can[b * T_ + tt * 16 + lq];
  }
#pragma unroll
  for (int r = 0; r < 4; r++) {
    float v0 = accPrev[r];
#pragma unroll
    for (int j = 0; j < NBINS; j++) {
      float d0 = v0 - mus[j];
      binacc[r][j] += mkPrev * __expf(d0 * d0 * nis2[j]);
    }
  }
#pragma unroll
  for (int r = 0; r < 4; r++)
#pragma unroll
    for (int j = 0; j < NBINS; j++) {
      float v = binacc[r][j];
      v += __shfl_xor(v, 1);
      v += __shfl_xor(v, 2);
      v += __shfl_xor(v, 4);
      v += __shfl_xor(v, 8);
      binacc[r][j] = v;
    }
  if (lq == 0) {
#pragma unroll
    for (int r = 0; r < 4; r++)
#pragma unroll
      for (int j = 0; j < NBINS; j++)
        partial[(wv * 16 + lk * 4 + r) * NBINS + j] = binacc[r][j];
  }
  __syncthreads();
  float* dst = &psum[(size_t)outb * (Q_ * NBINS)];
  for (int idx = tid; idx < Q_ * NBINS; idx += 256) {
    int q = idx / NBINS;
    int j = idx - q * NBINS;
    int m = q >> 4, r16 = q & 15;
    dst[idx] = partial[(m * 16 + r16) * NBINS + j] +
               partial[((2 + m) * 16 + r16) * NBINS + j];
  }
}

__global__ __launch_bounds__(256) void final_kernel(
    const float* __restrict__ rep, const float* __restrict__ rep_cur,
    const float* __restrict__ mask_session, const float* __restrict__ W_dense,
    const float* __restrict__ b_dense, const float* __restrict__ W_att,
    const float* __restrict__ b_att, const float* __restrict__ word_atten,
    const float* __restrict__ mask_hq, const float* __restrict__ psum,
    float* __restrict__ out) {
  __shared__ float lp[NB_ * Q_ * NBINS];
  __shared__ float pooled_sm[NB_ * NBINS];
  __shared__ float qproj[D_];
  __shared__ float scores_sm[NB_];
  int b = blockIdx.x, tid = threadIdx.x;
  {
    int nb = tid >> 5, q = tid & 31;
    int outb = b * NB_ + nb;
    float wa = word_atten[outb * Q_ + q] * mask_hq[outb * Q_ + q];
    const float* ps = &psum[(size_t)outb * (Q_ * NBINS) + q * NBINS];
#pragma unroll
    for (int j = 0; j < NBINS; j++)
      lp[(nb * Q_ + q) * NBINS + j] = logf(fmaxf(ps[j], 1e-10f)) * 0.01f * wa;
  }
  const float* rc = rep_cur + b * D_;
  float acc = b_att[tid];
  for (int k = 0; k < D_; k++) acc += rc[k] * W_att[k * D_ + tid];
  qproj[tid] = acc;
  __syncthreads();
  if (tid < NB_ * NBINS) {
    int nb = tid / NBINS, j = tid - nb * NBINS;
    float s = 0.f;
#pragma unroll
    for (int q = 0; q < Q_; q++) s += lp[(nb * Q_ + q) * NBINS + j];
    pooled_sm[nb * NBINS + j] = s;
  }
  int wv = tid >> 6, lane = tid & 63;
  for (int nn = wv; nn < NB_; nn += 4) {
    const float* rp = rep + ((size_t)b * NB_ + nn) * D_;
    float4 r4 = reinterpret_cast<const float4*>(rp)[lane];
    float4 q4 = *reinterpret_cast<float4*>(&qproj[lane * 4]);
    float s = r4.x * q4.x + r4.y * q4.y + r4.z * q4.z + r4.w * q4.w;
#pragma unroll
    for (int off = 32; off > 0; off >>= 1) s += __shfl_down(s, off);
    if (lane == 0) scores_sm[nn] = s * 0.0625f;
  }
  __syncthreads();
  if (tid == 0) {
    float sc[NB_];
    float mx = -1e30f;
    for (int nn = 0; nn < NB_; nn++) {
      float s = (mask_session[b * NB_ + nn] > 0.f) ? scores_sm[nn] : -1e9f;
      sc[nn] = s;
      mx = fmaxf(mx, s);
    }
    float den = 0.f;
    for (int nn = 0; nn < NB_; nn++) {
      sc[nn] = __expf(sc[nn] - mx);
      den += sc[nn];
    }
    float res = 0.f;
    for (int nn = 0; nn < NB_; nn++) {
      float ms = mask_session[b * NB_ + nn];
      float pw = b_dense[0];
      for (int j = 0; j < NBINS; j++)
        pw += pooled_sm[nn * NBINS + j] * ms * W_dense[j];
      res += tanhf(pw) * (sc[nn] / den);
    }
    out[b] = res;
  }
}

extern "C" void kernel_launch(void* const* d_in, const int* in_sizes, int n_in,
                              void* d_out, int out_size, void* d_ws,
                              size_t ws_size, hipStream_t stream) {
  const float* word_atten = (const float*)d_in[0];
  const float* hq = (const float*)d_in[1];
  const float* can = (const float*)d_in[2];
  const float* rep = (const float*)d_in[3];
  const float* rep_cur = (const float*)d_in[4];
  const float* mask_hq = (const float*)d_in[5];
  const float* mask_can = (const float*)d_in[6];
  const float* mask_session = (const float*)d_in[7];
  const float* W_dense = (const float*)d_in[8];
  const float* b_dense = (const float*)d_in[9];
  const float* W_att = (const float*)d_in[10];
  const float* b_att = (const float*)d_in[11];
  float* out = (float*)d_out;

  char* ws = (char*)d_ws;
  uint4* canH = (uint4*)(ws + CANH_OFF);
  uint4* canL = (uint4*)(ws + CANL_OFF);
  float* psum = (float*)(ws + PSUM_OFF);

  void* args[] = {(void*)&can,  (void*)&hq,        (void*)&word_atten,
                  (void*)&mask_hq, (void*)&mask_can, (void*)&rep,
                  (void*)&rep_cur, (void*)&mask_session, (void*)&W_dense,
                  (void*)&b_dense, (void*)&W_att,   (void*)&b_att,
                  (void*)&canH,  (void*)&canL,      (void*)&psum,
                  (void*)&out};
  hipError_t err = hipLaunchCooperativeKernel(
      (const void*)fused_kernel, dim3(512), dim3(256), args, 0, stream);
  if (err != hipSuccess) {
    // Fallback: R8's validated 3-kernel path.
    hipLaunchKernelGGL(split_kernel, dim3(512), dim3(256), 0, stream, can,
                       canH, canL);
    hipLaunchKernelGGL(pool_kernel, dim3(B_ * NB_), dim3(256), 0, stream, hq,
                       canH, canL, mask_can, psum);
    hipLaunchKernelGGL(final_kernel, dim3(B_), dim3(256), 0, stream, rep,
                       rep_cur, mask_session, W_dense, b_dense, W_att, b_att,
                       word_atten, mask_hq, psum, out);
  }
}

// Round 10
// 167.419 us; speedup vs baseline: 1.5736x; 1.5736x over previous
//
#include <hip/hip_runtime.h>

#define B_ 64
#define NB_ 8
#define Q_ 32
#define T_ 256
#define D_ 256
#define NBINS 11

typedef __attribute__((ext_vector_type(8))) short bf16x8;
typedef __attribute__((ext_vector_type(4))) float f32x4;
typedef unsigned short ushort_t;
typedef unsigned int uint_t;

// ws byte offsets: fragment-ordered bf16 hi/lo split of can + psum + cnt.
#define CANH_OFF 0u
#define CANL_OFF 8388608u
#define PSUM_OFF 16777216u
#define CNT_OFF (16777216u + 720896u)

__device__ inline ushort_t bf16_rnd(float f) {
  uint_t u = __float_as_uint(f);
  return (ushort_t)((u + 0x8000u) >> 16);
}
__device__ inline uint_t pack2(ushort_t a, ushort_t b) {
  return (uint_t)a | ((uint_t)b << 16);
}

// ---------------------------------------------------------------------------
// split_kernel (R8-validated): can row-norm + hi/lo bf16 split -> fragment-
// ordered ws. Grid 512 = (b 64, 32-row chunk 8). Also zeroes cnt[64] for the
// pool kernel's last-arriver protocol (stream order makes this visible).
// ---------------------------------------------------------------------------
__global__ __launch_bounds__(256) void split_kernel(
    const float* __restrict__ can, uint4* __restrict__ canH,
    uint4* __restrict__ canL, uint_t* __restrict__ cnt) {
  __shared__ __align__(16) ushort_t sm_hi[32 * 264];
  __shared__ __align__(16) ushort_t sm_lo[32 * 264];
  int blk = blockIdx.x;
  int tid = threadIdx.x;
  if (tid == 0 && blk < 64) cnt[blk] = 0u;  // ws is poisoned each launch
  int b = blk >> 3, ch = blk & 7;
  const float* src = can + ((size_t)b * T_ + ch * 32) * D_;
  int tilebase = b * 16 + ch * 2;

#pragma unroll
  for (int it = 0; it < 4; it++) {
    int flat = it * 2048 + tid * 8;
    int row = flat >> 8, col = flat & 255;
    const float* p = src + row * D_ + col;
    float4 x = reinterpret_cast<const float4*>(p)[0];
    float4 y = reinterpret_cast<const float4*>(p)[1];
    float s = x.x * x.x + x.y * x.y + x.z * x.z + x.w * x.w +
              y.x * y.x + y.y * y.y + y.z * y.z + y.w * y.w;
    // 32 consecutive threads cover one 256-col row
    s += __shfl_xor(s, 1);
    s += __shfl_xor(s, 2);
    s += __shfl_xor(s, 4);
    s += __shfl_xor(s, 8);
    s += __shfl_xor(s, 16);
    float inv = 1.0f / fmaxf(sqrtf(s), 1e-10f);
    float v[8] = {x.x, x.y, x.z, x.w, y.x, y.y, y.z, y.w};
    ushort_t h[8], l[8];
#pragma unroll
    for (int j = 0; j < 8; j++) {
      float sv = v[j] * inv;
      h[j] = bf16_rnd(sv);
      float hf = __uint_as_float(((uint_t)h[j]) << 16);
      l[j] = bf16_rnd(sv - hf);
    }
    uint4 ph = {pack2(h[0], h[1]), pack2(h[2], h[3]), pack2(h[4], h[5]),
                pack2(h[6], h[7])};
    uint4 pl = {pack2(l[0], l[1]), pack2(l[2], l[3]), pack2(l[4], l[5]),
                pack2(l[6], l[7])};
    *reinterpret_cast<uint4*>(&sm_hi[row * 264 + col]) = ph;
    *reinterpret_cast<uint4*>(&sm_lo[row * 264 + col]) = pl;
  }
  __syncthreads();
  int wv = tid >> 6, lane = tid & 63;
  int tl = wv >> 1, part = wv & 1;  // tile-local 0/1, hi/lo part
  int lq = lane & 15, lk = lane >> 4;
  const ushort_t* smp = part ? sm_lo : sm_hi;
  uint4* dst = part ? canL : canH;
#pragma unroll
  for (int kk = 0; kk < 8; kk++) {
    const ushort_t* a = &smp[(tl * 16 + lq) * 264 + kk * 32 + lk * 8];
    dst[((size_t)(tilebase + tl) * 8 + kk) * 64 + lane] =
        *reinterpret_cast<const uint4*>(a);
  }
}

// ---------------------------------------------------------------------------
// pool_kernel: R8-validated body (register A-split, barrier-free deferred-
// bins 3-MFMA pipeline, shfl+LDS reduce, single psum write), PLUS fused
// final epilogue via last-arriver: after psum write, release-fence +
// atomicAdd(&cnt[b]); the 8th (last) block of each b runs the per-b final
// (log-pool + W_att proj + masked softmax + tanh dense). All 8 blocks of b
// share an XCD (blockIdx%8 = b%8) so psum stays L2-local. Saves the third
// dispatch. (R9 lesson: grid.sync costs ~60us/sync — last-arriver is the
// cheap fusion.)
// ---------------------------------------------------------------------------
__global__ __launch_bounds__(256, 2) void pool_kernel(
    const float* __restrict__ hq, const uint4* __restrict__ canH,
    const uint4* __restrict__ canL, const float* __restrict__ mask_can,
    const float* __restrict__ word_atten, const float* __restrict__ mask_hq,
    const float* __restrict__ rep, const float* __restrict__ rep_cur,
    const float* __restrict__ mask_session, const float* __restrict__ W_dense,
    const float* __restrict__ b_dense, const float* __restrict__ W_att,
    const float* __restrict__ b_att, float* __restrict__ psum,
    uint_t* __restrict__ cnt, float* __restrict__ out) {
  // 3168 floats = 12.7 KB: pool uses first 704 (partial); final overlays all.
  __shared__ float smbuf[3168];
  __shared__ int isLast;
  float* partial = smbuf;

  const float mus[NBINS] = {1.0f, 0.9f, 0.7f, 0.5f, 0.3f, 0.1f,
                            -0.1f, -0.3f, -0.5f, -0.7f, -0.9f};
  const float nis2[NBINS] = {-5.0e5f, -50.f, -50.f, -50.f, -50.f, -50.f,
                             -50.f, -50.f, -50.f, -50.f, -50.f};

  int i = blockIdx.x;
  int b = i & 63;  // XCD = i%8 = b%8
  int nb = i >> 6;
  int outb = b * NB_ + nb;
  int tid = threadIdx.x;
  int wv = tid >> 6, lane = tid & 63;
  int lq = lane & 15, lk = lane >> 4;
  int mtile = wv & 1, tq = wv >> 1;

  // ---- A fragments: register norm + hi/lo split (R6/R8-validated) ----
  const float* arow =
      hq + (size_t)outb * (Q_ * D_) + (size_t)(mtile * 16 + lq) * D_;
  float sumsq = 0.f;
#pragma unroll
  for (int kk = 0; kk < 8; kk++) {
    const float* p = arow + kk * 32 + lk * 8;
    float4 x = reinterpret_cast<const float4*>(p)[0];
    float4 y = reinterpret_cast<const float4*>(p)[1];
    sumsq += x.x * x.x + x.y * x.y + x.z * x.z + x.w * x.w +
             y.x * y.x + y.y * y.y + y.z * y.z + y.w * y.w;
  }
  sumsq += __shfl_xor(sumsq, 16);
  sumsq += __shfl_xor(sumsq, 32);
  float ainv = 1.0f / fmaxf(sqrtf(sumsq), 1e-10f);

  bf16x8 ah[8], al[8];
#pragma unroll
  for (int kk = 0; kk < 8; kk++) {
    const float* p = arow + kk * 32 + lk * 8;  // L1-hot reload
    float4 x = reinterpret_cast<const float4*>(p)[0];
    float4 y = reinterpret_cast<const float4*>(p)[1];
    float v[8] = {x.x, x.y, x.z, x.w, y.x, y.y, y.z, y.w};
    union { bf16x8 v8; ushort_t u[8]; } H, L;
#pragma unroll
    for (int j = 0; j < 8; j++) {
      float s = v[j] * ainv;
      ushort_t h = bf16_rnd(s);
      float hf = __uint_as_float(((uint_t)h) << 16);
      H.u[j] = h;
      L.u[j] = bf16_rnd(s - hf);
    }
    ah[kk] = H.v8;
    al[kk] = L.v8;
  }

  float binacc[4][NBINS];
#pragma unroll
  for (int r = 0; r < 4; r++)
#pragma unroll
    for (int j = 0; j < NBINS; j++) binacc[r][j] = 0.0f;

  f32x4 accPrev;
  float mkPrev = 0.0f;

  {  // tile 0
    int tt = tq * 8;
    size_t bbase = (size_t)(b * 16 + tt) * 8 * 64 + lane;
    f32x4 acc = {0.f, 0.f, 0.f, 0.f};
#pragma unroll
    for (int kk = 0; kk < 8; kk++) {
      bf16x8 bh = *reinterpret_cast<const bf16x8*>(&canH[bbase + kk * 64]);
      bf16x8 bl = *reinterpret_cast<const bf16x8*>(&canL[bbase + kk * 64]);
      acc = __builtin_amdgcn_mfma_f32_16x16x32_bf16(ah[kk], bh, acc, 0, 0, 0);
      acc = __builtin_amdgcn_mfma_f32_16x16x32_bf16(al[kk], bh, acc, 0, 0, 0);
      acc = __builtin_amdgcn_mfma_f32_16x16x32_bf16(ah[kk], bl, acc, 0, 0, 0);
    }
    accPrev = acc;
    mkPrev = mask_can[b * T_ + tt * 16 + lq];
  }

  for (int ti = 1; ti < 8; ti++) {  // load(ti) issued before bins(ti-1)
    int tt = tq * 8 + ti;
    size_t bbase = (size_t)(b * 16 + tt) * 8 * 64 + lane;
    bf16x8 bh[8], bl[8];
#pragma unroll
    for (int kk = 0; kk < 8; kk++) {
      bh[kk] = *reinterpret_cast<const bf16x8*>(&canH[bbase + kk * 64]);
      bl[kk] = *reinterpret_cast<const bf16x8*>(&canL[bbase + kk * 64]);
    }
    // C/D: col(t)=lane&15, row(q)=(lane>>4)*4+reg  [R4-validated]
#pragma unroll
    for (int r = 0; r < 4; r++) {
      float v0 = accPrev[r];
#pragma unroll
      for (int j = 0; j < NBINS; j++) {
        float d0 = v0 - mus[j];
        binacc[r][j] += mkPrev * __expf(d0 * d0 * nis2[j]);
      }
    }
    f32x4 acc = {0.f, 0.f, 0.f, 0.f};
#pragma unroll
    for (int kk = 0; kk < 8; kk++) {
      acc = __builtin_amdgcn_mfma_f32_16x16x32_bf16(ah[kk], bh[kk], acc, 0, 0, 0);
      acc = __builtin_amdgcn_mfma_f32_16x16x32_bf16(al[kk], bh[kk], acc, 0, 0, 0);
      acc = __builtin_amdgcn_mfma_f32_16x16x32_bf16(ah[kk], bl[kk], acc, 0, 0, 0);
    }
    accPrev = acc;
    mkPrev = mask_can[b * T_ + tt * 16 + lq];
  }
#pragma unroll
  for (int r = 0; r < 4; r++) {  // bins of last tile
    float v0 = accPrev[r];
#pragma unroll
    for (int j = 0; j < NBINS; j++) {
      float d0 = v0 - mus[j];
      binacc[r][j] += mkPrev * __expf(d0 * d0 * nis2[j]);
    }
  }

  // ---- reduce over the 16 t-cols (lq) held by this wave ----
#pragma unroll
  for (int r = 0; r < 4; r++)
#pragma unroll
    for (int j = 0; j < NBINS; j++) {
      float v = binacc[r][j];
      v += __shfl_xor(v, 1);
      v += __shfl_xor(v, 2);
      v += __shfl_xor(v, 4);
      v += __shfl_xor(v, 8);
      binacc[r][j] = v;
    }
  if (lq == 0) {
#pragma unroll
    for (int r = 0; r < 4; r++)
#pragma unroll
      for (int j = 0; j < NBINS; j++)
        partial[(wv * 16 + lk * 4 + r) * NBINS + j] = binacc[r][j];
  }
  __syncthreads();

  // combine tq halves; single psum write. STRIDED over 352 (R3 lesson).
  float* dst = &psum[(size_t)outb * (Q_ * NBINS)];
  for (int idx = tid; idx < Q_ * NBINS; idx += 256) {
    int q = idx / NBINS;
    int j = idx - q * NBINS;
    int m = q >> 4, r16 = q & 15;
    dst[idx] = partial[(m * 16 + r16) * NBINS + j] +
               partial[((2 + m) * 16 + r16) * NBINS + j];
  }

  // ---- last-arriver rendezvous for b ----
  __threadfence();   // release: each thread's psum stores visible device-wide
  __syncthreads();   // all threads' writes issued before the count
  if (tid == 0) {
    uint_t old = atomicAdd(&cnt[b], 1u);
    isLast = (old == (uint_t)(NB_ - 1));
  }
  __syncthreads();   // also separates partial reads from the lp overlay below
  if (!isLast) return;
  __threadfence();   // acquire: see the other 7 blocks' psum

  // ---- fused final epilogue for this b (R7/R8-validated body) ----
  float* lp = smbuf;                       // 2816 f
  float* pooled_sm = smbuf + 2816;         // 88 f
  float* qproj = smbuf + 2904;             // 256 f
  float* scores_sm = smbuf + 3160;         // 8 f
  {
    int nb2 = tid >> 5, q = tid & 31;
    int ob = b * NB_ + nb2;
    float wa = word_atten[ob * Q_ + q] * mask_hq[ob * Q_ + q];
    const float* ps = &psum[(size_t)ob * (Q_ * NBINS) + q * NBINS];
#pragma unroll
    for (int j = 0; j < NBINS; j++)
      lp[(nb2 * Q_ + q) * NBINS + j] = logf(fmaxf(ps[j], 1e-10f)) * 0.01f * wa;
  }

  const float* rc = rep_cur + b * D_;
  float acc2 = b_att[tid];
  for (int k = 0; k < D_; k++) acc2 += rc[k] * W_att[k * D_ + tid];
  qproj[tid] = acc2;
  __syncthreads();

  if (tid < NB_ * NBINS) {
    int nb2 = tid / NBINS, j = tid - nb2 * NBINS;
    float s = 0.f;
#pragma unroll
    for (int q = 0; q < Q_; q++) s += lp[(nb2 * Q_ + q) * NBINS + j];
    pooled_sm[nb2 * NBINS + j] = s;
  }

  for (int nn = wv; nn < NB_; nn += 4) {
    const float* rp = rep + ((size_t)b * NB_ + nn) * D_;
    float4 r4 = reinterpret_cast<const float4*>(rp)[lane];
    float4 q4 = *reinterpret_cast<float4*>(&qproj[lane * 4]);
    float s = r4.x * q4.x + r4.y * q4.y + r4.z * q4.z + r4.w * q4.w;
#pragma unroll
    for (int off = 32; off > 0; off >>= 1) s += __shfl_down(s, off);
    if (lane == 0) scores_sm[nn] = s * 0.0625f;  // 1/sqrt(256)
  }
  __syncthreads();

  if (tid == 0) {
    float sc[NB_];
    float mx = -1e30f;
    for (int nn = 0; nn < NB_; nn++) {
      float s = (mask_session[b * NB_ + nn] > 0.f) ? scores_sm[nn] : -1e9f;
      sc[nn] = s;
      mx = fmaxf(mx, s);
    }
    float den = 0.f;
    for (int nn = 0; nn < NB_; nn++) {
      sc[nn] = __expf(sc[nn] - mx);
      den += sc[nn];
    }
    float res = 0.f;
    for (int nn = 0; nn < NB_; nn++) {
      float ms = mask_session[b * NB_ + nn];
      float pw = b_dense[0];
      for (int j = 0; j < NBINS; j++)
        pw += pooled_sm[nn * NBINS + j] * ms * W_dense[j];
      res += tanhf(pw) * (sc[nn] / den);
    }
    out[b] = res;
  }
}

// ---------------------------------------------------------------------------
// ws: canH/canL (16.8 MB) + psum (512 x 352 f) + cnt[64] (zeroed by split).
// 2 dispatches total.
// ---------------------------------------------------------------------------
extern "C" void kernel_launch(void* const* d_in, const int* in_sizes, int n_in,
                              void* d_out, int out_size, void* d_ws,
                              size_t ws_size, hipStream_t stream) {
  const float* word_atten = (const float*)d_in[0];
  const float* hq = (const float*)d_in[1];
  const float* can = (const float*)d_in[2];
  const float* rep = (const float*)d_in[3];
  const float* rep_cur = (const float*)d_in[4];
  const float* mask_hq = (const float*)d_in[5];
  const float* mask_can = (const float*)d_in[6];
  const float* mask_session = (const float*)d_in[7];
  const float* W_dense = (const float*)d_in[8];
  const float* b_dense = (const float*)d_in[9];
  const float* W_att = (const float*)d_in[10];
  const float* b_att = (const float*)d_in[11];
  float* out = (float*)d_out;

  char* ws = (char*)d_ws;
  uint4* canH = (uint4*)(ws + CANH_OFF);
  uint4* canL = (uint4*)(ws + CANL_OFF);
  float* psum = (float*)(ws + PSUM_OFF);
  uint_t* cnt = (uint_t*)(ws + CNT_OFF);

  hipLaunchKernelGGL(split_kernel, dim3(512), dim3(256), 0, stream, can, canH,
                     canL, cnt);
  hipLaunchKernelGGL(pool_kernel, dim3(B_ * NB_), dim3(256), 0, stream, hq,
                     canH, canL, mask_can, word_atten, mask_hq, rep, rep_cur,
                     mask_session, W_dense, b_dense, W_att, b_att, psum, cnt,
                     out);
}

// Round 11
// 126.551 us; speedup vs baseline: 2.0818x; 1.3229x over previous
//
#include <hip/hip_runtime.h>

#define B_ 64
#define NB_ 8
#define Q_ 32
#define T_ 256
#define D_ 256
#define NBINS 11

typedef __attribute__((ext_vector_type(8))) short bf16x8;
typedef __attribute__((ext_vector_type(4))) float f32x4;
typedef unsigned short ushort_t;
typedef unsigned int uint_t;

// ws byte offsets: fragment-ordered bf16 hi/lo split of can. Nothing else.
#define CANH_OFF 0u
#define CANL_OFF 8388608u

__device__ inline ushort_t bf16_rnd(float f) {
  uint_t u = __float_as_uint(f);
  return (ushort_t)((u + 0x8000u) >> 16);
}
__device__ inline uint_t pack2(ushort_t a, ushort_t b) {
  return (uint_t)a | ((uint_t)b << 16);
}

// ---------------------------------------------------------------------------
// split_kernel (R8-validated): can row-norm + hi/lo bf16 split -> fragment-
// ordered ws. Grid 512 = (b 64, 32-row chunk 8). Also zeroes out[64] for the
// pool kernel's atomicAdd accumulation (stream order guarantees visibility;
// harness poisons d_out to 0xAA before every timed launch).
// ---------------------------------------------------------------------------
__global__ __launch_bounds__(256) void split_kernel(
    const float* __restrict__ can, uint4* __restrict__ canH,
    uint4* __restrict__ canL, float* __restrict__ out) {
  __shared__ __align__(16) ushort_t sm_hi[32 * 264];
  __shared__ __align__(16) ushort_t sm_lo[32 * 264];
  int blk = blockIdx.x;
  int tid = threadIdx.x;
  if (tid == 0 && blk < B_) out[blk] = 0.0f;
  int b = blk >> 3, ch = blk & 7;
  const float* src = can + ((size_t)b * T_ + ch * 32) * D_;
  int tilebase = b * 16 + ch * 2;

#pragma unroll
  for (int it = 0; it < 4; it++) {
    int flat = it * 2048 + tid * 8;
    int row = flat >> 8, col = flat & 255;
    const float* p = src + row * D_ + col;
    float4 x = reinterpret_cast<const float4*>(p)[0];
    float4 y = reinterpret_cast<const float4*>(p)[1];
    float s = x.x * x.x + x.y * x.y + x.z * x.z + x.w * x.w +
              y.x * y.x + y.y * y.y + y.z * y.z + y.w * y.w;
    // 32 consecutive threads cover one 256-col row
    s += __shfl_xor(s, 1);
    s += __shfl_xor(s, 2);
    s += __shfl_xor(s, 4);
    s += __shfl_xor(s, 8);
    s += __shfl_xor(s, 16);
    float inv = 1.0f / fmaxf(sqrtf(s), 1e-10f);
    float v[8] = {x.x, x.y, x.z, x.w, y.x, y.y, y.z, y.w};
    ushort_t h[8], l[8];
#pragma unroll
    for (int j = 0; j < 8; j++) {
      float sv = v[j] * inv;
      h[j] = bf16_rnd(sv);
      float hf = __uint_as_float(((uint_t)h[j]) << 16);
      l[j] = bf16_rnd(sv - hf);
    }
    uint4 ph = {pack2(h[0], h[1]), pack2(h[2], h[3]), pack2(h[4], h[5]),
                pack2(h[6], h[7])};
    uint4 pl = {pack2(l[0], l[1]), pack2(l[2], l[3]), pack2(l[4], l[5]),
                pack2(l[6], l[7])};
    *reinterpret_cast<uint4*>(&sm_hi[row * 264 + col]) = ph;
    *reinterpret_cast<uint4*>(&sm_lo[row * 264 + col]) = pl;
  }
  __syncthreads();
  int wv = tid >> 6, lane = tid & 63;
  int tl = wv >> 1, part = wv & 1;  // tile-local 0/1, hi/lo part
  int lq = lane & 15, lk = lane >> 4;
  const ushort_t* smp = part ? sm_lo : sm_hi;
  uint4* dst = part ? canL : canH;
#pragma unroll
  for (int kk = 0; kk < 8; kk++) {
    const ushort_t* a = &smp[(tl * 16 + lq) * 264 + kk * 32 + lk * 8];
    dst[((size_t)(tilebase + tl) * 8 + kk) * 64 + lane] =
        *reinterpret_cast<const uint4*>(a);
  }
}

// ---------------------------------------------------------------------------
// pool_kernel: R8-validated body (register A-split, barrier-free deferred-
// bins 3-MFMA pipeline, shfl+LDS reduce) + SELF-CONTAINED epilogue:
// each block holds the complete bin sums for its (b,nb) (all 256 t are
// in-block), and the softmax attention weights depend only on INPUTS
// (rep, rep_cur, W_att, b_att) — so each block computes log-pool, its own
// pooled.W_dense, the full 8-way masked softmax (duplicated, ~0.4us device-
// wide), and atomicAdd(&out[b], tanh(pw)*attn_nb). 512 total atomics.
// NO fence, NO rendezvous, NO psum round-trip, NO third dispatch.
// (R9 lesson: grid.sync ~60us/sync. R10 lesson: per-block __threadfence
// costs ~60us aggregate. R5 lesson: 720k atomics bad — 512 is fine.)
// XCD swizzle: blockIdx%8 = b%8 -> can[b] fragments stay in one L2.
// ---------------------------------------------------------------------------
__global__ __launch_bounds__(256, 2) void pool_kernel(
    const float* __restrict__ hq, const uint4* __restrict__ canH,
    const uint4* __restrict__ canL, const float* __restrict__ mask_can,
    const float* __restrict__ word_atten, const float* __restrict__ mask_hq,
    const float* __restrict__ rep, const float* __restrict__ rep_cur,
    const float* __restrict__ mask_session, const float* __restrict__ W_dense,
    const float* __restrict__ b_dense, const float* __restrict__ W_att,
    const float* __restrict__ b_att, float* __restrict__ out) {
  // LDS: partial[704] | lp[352] | qproj[256] | scores[8] | pooled[11]
  __shared__ float smbuf[1331];
  float* partial = smbuf;            // 704
  float* lp_sm = smbuf + 704;        // 352
  float* qproj = smbuf + 1056;       // 256
  float* scores_sm = smbuf + 1312;   // 8
  float* pooled_sm = smbuf + 1320;   // 11

  const float mus[NBINS] = {1.0f, 0.9f, 0.7f, 0.5f, 0.3f, 0.1f,
                            -0.1f, -0.3f, -0.5f, -0.7f, -0.9f};
  const float nis2[NBINS] = {-5.0e5f, -50.f, -50.f, -50.f, -50.f, -50.f,
                             -50.f, -50.f, -50.f, -50.f, -50.f};

  int i = blockIdx.x;
  int b = i & 63;  // XCD = i%8 = b%8
  int nb = i >> 6;
  int outb = b * NB_ + nb;
  int tid = threadIdx.x;
  int wv = tid >> 6, lane = tid & 63;
  int lq = lane & 15, lk = lane >> 4;
  int mtile = wv & 1, tq = wv >> 1;

  // ---- A fragments: register norm + hi/lo split (R6/R8-validated) ----
  const float* arow =
      hq + (size_t)outb * (Q_ * D_) + (size_t)(mtile * 16 + lq) * D_;
  float sumsq = 0.f;
#pragma unroll
  for (int kk = 0; kk < 8; kk++) {
    const float* p = arow + kk * 32 + lk * 8;
    float4 x = reinterpret_cast<const float4*>(p)[0];
    float4 y = reinterpret_cast<const float4*>(p)[1];
    sumsq += x.x * x.x + x.y * x.y + x.z * x.z + x.w * x.w +
             y.x * y.x + y.y * y.y + y.z * y.z + y.w * y.w;
  }
  sumsq += __shfl_xor(sumsq, 16);
  sumsq += __shfl_xor(sumsq, 32);
  float ainv = 1.0f / fmaxf(sqrtf(sumsq), 1e-10f);

  bf16x8 ah[8], al[8];
#pragma unroll
  for (int kk = 0; kk < 8; kk++) {
    const float* p = arow + kk * 32 + lk * 8;  // L1-hot reload
    float4 x = reinterpret_cast<const float4*>(p)[0];
    float4 y = reinterpret_cast<const float4*>(p)[1];
    float v[8] = {x.x, x.y, x.z, x.w, y.x, y.y, y.z, y.w};
    union { bf16x8 v8; ushort_t u[8]; } H, L;
#pragma unroll
    for (int j = 0; j < 8; j++) {
      float s = v[j] * ainv;
      ushort_t h = bf16_rnd(s);
      float hf = __uint_as_float(((uint_t)h) << 16);
      H.u[j] = h;
      L.u[j] = bf16_rnd(s - hf);
    }
    ah[kk] = H.v8;
    al[kk] = L.v8;
  }

  float binacc[4][NBINS];
#pragma unroll
  for (int r = 0; r < 4; r++)
#pragma unroll
    for (int j = 0; j < NBINS; j++) binacc[r][j] = 0.0f;

  f32x4 accPrev;
  float mkPrev = 0.0f;

  {  // tile 0
    int tt = tq * 8;
    size_t bbase = (size_t)(b * 16 + tt) * 8 * 64 + lane;
    f32x4 acc = {0.f, 0.f, 0.f, 0.f};
#pragma unroll
    for (int kk = 0; kk < 8; kk++) {
      bf16x8 bh = *reinterpret_cast<const bf16x8*>(&canH[bbase + kk * 64]);
      bf16x8 bl = *reinterpret_cast<const bf16x8*>(&canL[bbase + kk * 64]);
      acc = __builtin_amdgcn_mfma_f32_16x16x32_bf16(ah[kk], bh, acc, 0, 0, 0);
      acc = __builtin_amdgcn_mfma_f32_16x16x32_bf16(al[kk], bh, acc, 0, 0, 0);
      acc = __builtin_amdgcn_mfma_f32_16x16x32_bf16(ah[kk], bl, acc, 0, 0, 0);
    }
    accPrev = acc;
    mkPrev = mask_can[b * T_ + tt * 16 + lq];
  }

  for (int ti = 1; ti < 8; ti++) {  // load(ti) issued before bins(ti-1)
    int tt = tq * 8 + ti;
    size_t bbase = (size_t)(b * 16 + tt) * 8 * 64 + lane;
    bf16x8 bh[8], bl[8];
#pragma unroll
    for (int kk = 0; kk < 8; kk++) {
      bh[kk] = *reinterpret_cast<const bf16x8*>(&canH[bbase + kk * 64]);
      bl[kk] = *reinterpret_cast<const bf16x8*>(&canL[bbase + kk * 64]);
    }
    // C/D: col(t)=lane&15, row(q)=(lane>>4)*4+reg  [R4-validated]
#pragma unroll
    for (int r = 0; r < 4; r++) {
      float v0 = accPrev[r];
#pragma unroll
      for (int j = 0; j < NBINS; j++) {
        float d0 = v0 - mus[j];
        binacc[r][j] += mkPrev * __expf(d0 * d0 * nis2[j]);
      }
    }
    f32x4 acc = {0.f, 0.f, 0.f, 0.f};
#pragma unroll
    for (int kk = 0; kk < 8; kk++) {
      acc = __builtin_amdgcn_mfma_f32_16x16x32_bf16(ah[kk], bh[kk], acc, 0, 0, 0);
      acc = __builtin_amdgcn_mfma_f32_16x16x32_bf16(al[kk], bh[kk], acc, 0, 0, 0);
      acc = __builtin_amdgcn_mfma_f32_16x16x32_bf16(ah[kk], bl[kk], acc, 0, 0, 0);
    }
    accPrev = acc;
    mkPrev = mask_can[b * T_ + tt * 16 + lq];
  }
#pragma unroll
  for (int r = 0; r < 4; r++) {  // bins of last tile
    float v0 = accPrev[r];
#pragma unroll
    for (int j = 0; j < NBINS; j++) {
      float d0 = v0 - mus[j];
      binacc[r][j] += mkPrev * __expf(d0 * d0 * nis2[j]);
    }
  }

  // ---- reduce over the 16 t-cols (lq) held by this wave ----
#pragma unroll
  for (int r = 0; r < 4; r++)
#pragma unroll
    for (int j = 0; j < NBINS; j++) {
      float v = binacc[r][j];
      v += __shfl_xor(v, 1);
      v += __shfl_xor(v, 2);
      v += __shfl_xor(v, 4);
      v += __shfl_xor(v, 8);
      binacc[r][j] = v;
    }
  if (lq == 0) {
#pragma unroll
    for (int r = 0; r < 4; r++)
#pragma unroll
      for (int j = 0; j < NBINS; j++)
        partial[(wv * 16 + lk * 4 + r) * NBINS + j] = binacc[r][j];
  }
  __syncthreads();

  // ---- in-block epilogue (no global round-trip) ----
  // (a) combine tq halves + log-pool * word_atten * mask_hq -> lp_sm.
  //     STRIDED over 352 items (R3 lesson).
  for (int idx = tid; idx < Q_ * NBINS; idx += 256) {
    int q = idx / NBINS;
    int j = idx - q * NBINS;
    int m = q >> 4, r16 = q & 15;
    float sum = partial[(m * 16 + r16) * NBINS + j] +
                partial[((2 + m) * 16 + r16) * NBINS + j];
    float wa = word_atten[outb * Q_ + q] * mask_hq[outb * Q_ + q];
    lp_sm[idx] = logf(fmaxf(sum, 1e-10f)) * 0.01f * wa;
  }

  // (b) W_att projection (input-only; duplicated across the 8 nb-blocks of b)
  {
    const float* rc = rep_cur + b * D_;
    float acc2 = b_att[tid];
    for (int k = 0; k < D_; k++) acc2 += rc[k] * W_att[k * D_ + tid];
    qproj[tid] = acc2;
  }
  __syncthreads();

  // (c) pooled[j] = sum_q lp (this block's nb only)
  if (tid < NBINS) {
    float s = 0.f;
#pragma unroll
    for (int q = 0; q < Q_; q++) s += lp_sm[q * NBINS + tid];
    pooled_sm[tid] = s;
  }

  // (d) all 8 attention scores (each wave does 2)
  for (int nn = wv; nn < NB_; nn += 4) {
    const float* rp = rep + ((size_t)b * NB_ + nn) * D_;
    float4 r4 = reinterpret_cast<const float4*>(rp)[lane];
    float4 q4 = *reinterpret_cast<float4*>(&qproj[lane * 4]);
    float s = r4.x * q4.x + r4.y * q4.y + r4.z * q4.z + r4.w * q4.w;
#pragma unroll
    for (int off = 32; off > 0; off >>= 1) s += __shfl_down(s, off);
    if (lane == 0) scores_sm[nn] = s * 0.0625f;  // 1/sqrt(256)
  }
  __syncthreads();

  // (e) masked softmax (local, deterministic) + this nb's contribution
  if (tid == 0) {
    float sc[NB_];
    float mx = -1e30f;
    for (int nn = 0; nn < NB_; nn++) {
      float s = (mask_session[b * NB_ + nn] > 0.f) ? scores_sm[nn] : -1e9f;
      sc[nn] = s;
      mx = fmaxf(mx, s);
    }
    float den = 0.f;
    for (int nn = 0; nn < NB_; nn++) {
      sc[nn] = __expf(sc[nn] - mx);
      den += sc[nn];
    }
    float ms = mask_session[b * NB_ + nb];
    float pw = b_dense[0];
#pragma unroll
    for (int j = 0; j < NBINS; j++) pw += pooled_sm[j] * ms * W_dense[j];
    float res = tanhf(pw) * (sc[nb] / den);
    atomicAdd(&out[b], res);  // 512 total atomics; out zeroed by split_kernel
  }
}

// ---------------------------------------------------------------------------
// ws: canH/canL only (16.8 MB). 2 dispatches total; no psum, no fences.
// ---------------------------------------------------------------------------
extern "C" void kernel_launch(void* const* d_in, const int* in_sizes, int n_in,
                              void* d_out, int out_size, void* d_ws,
                              size_t ws_size, hipStream_t stream) {
  const float* word_atten = (const float*)d_in[0];
  const float* hq = (const float*)d_in[1];
  const float* can = (const float*)d_in[2];
  const float* rep = (const float*)d_in[3];
  const float* rep_cur = (const float*)d_in[4];
  const float* mask_hq = (const float*)d_in[5];
  const float* mask_can = (const float*)d_in[6];
  const float* mask_session = (const float*)d_in[7];
  const float* W_dense = (const float*)d_in[8];
  const float* b_dense = (const float*)d_in[9];
  const float* W_att = (const float*)d_in[10];
  const float* b_att = (const float*)d_in[11];
  float* out = (float*)d_out;

  char* ws = (char*)d_ws;
  uint4* canH = (uint4*)(ws + CANH_OFF);
  uint4* canL = (uint4*)(ws + CANL_OFF);

  hipLaunchKernelGGL(split_kernel, dim3(512), dim3(256), 0, stream, can, canH,
                     canL, out);
  hipLaunchKernelGGL(pool_kernel, dim3(B_ * NB_), dim3(256), 0, stream, hq,
                     canH, canL, mask_can, word_atten, mask_hq, rep, rep_cur,
                     mask_session, W_dense, b_dense, W_att, b_att, out);
}